// Round 2
// baseline (557.890 us; speedup 1.0000x reference)
//
#include <hip/hip_runtime.h>
#include <hip/hip_bf16.h>
#include <math.h>

#define NNODES 100000
#define NEDGES 1600000
#define FIN 256
#define HDIM 128
#define NGRAPH 128
#define NCLS 10
#define NEG 0.2f

#define NBUCK 98            // buckets of 1024 dst nodes
#define EPB 4096            // edges per bin_place block
#define EBLK ((NEDGES + EPB - 1) / EPB)   // 391

typedef short bf8 __attribute__((ext_vector_type(8)));
typedef float f4 __attribute__((ext_vector_type(4)));

__device__ __forceinline__ float lrelu(float x) { return x > 0.f ? x : NEG * x; }

__device__ __forceinline__ unsigned short f2bf(float f) {
  union { float f; unsigned int u; } v; v.f = f;
  unsigned int r = v.u + 0x7fffu + ((v.u >> 16) & 1u);   // round-nearest-even
  return (unsigned short)(r >> 16);
}
__device__ __forceinline__ float bf2f(unsigned short u) {
  union { unsigned int u; float f; } v; v.u = ((unsigned int)u) << 16; return v.f;
}
__device__ __forceinline__ float bf_lo(unsigned int p) {
  union { unsigned int u; float f; } v; v.u = p << 16; return v.f;
}
__device__ __forceinline__ float bf_hi(unsigned int p) {
  union { unsigned int u; float f; } v; v.u = p & 0xffff0000u; return v.f;
}
__device__ __forceinline__ float fast_rcp(float x) {
  float r;
  asm("v_rcp_f32 %0, %1" : "=v"(r) : "v"(x));
  return r;
}
__device__ __forceinline__ unsigned cvt_pk_bf16(float lo, float hi) {
  unsigned r;
  asm("v_cvt_pk_bf16_f32 %0, %1, %2" : "=v"(r) : "v"(lo), "v"(hi));
  return r;
}

// ---------------- one-shot weight convert+transpose: w[K][128] -> wt[128][K] -
__global__ __launch_bounds__(256) void convert_transpose(const float* __restrict__ w,
                                                         unsigned short* __restrict__ wt,
                                                         int K) {
  int i = blockIdx.x * 256 + threadIdx.x;
  if (i >= K * 128) return;
  int k = i >> 7, n = i & 127;
  wt[n * K + k] = f2bf(w[(size_t)k * 128 + n]);
}

// ---------------- MFMA GEMM: 64-row tiles, depth-2 prefetch (STATIC buffers) -
// Block tile 64 x 128 (grid ~1563 -> ~6 blocks/CU). Wave w: m-tile w (16 rows).
// K-loop unrolled x2 so buffer selection is compile-time (runtime-indexed
// register arrays spill to scratch -- R11 lesson: 110MB scratch writes).
__global__ __launch_bounds__(256) void gemm_mfma(const void* __restrict__ Av,
                                                 int a_bf16,
                                                 const unsigned short* __restrict__ Bt,
                                                 const float* __restrict__ bias,
                                                 unsigned short* __restrict__ Cb,
                                                 unsigned int* __restrict__ Cp,
                                                 const float* __restrict__ a_src,
                                                 const float* __restrict__ a_dst,
                                                 float* __restrict__ o_as,
                                                 float* __restrict__ o_ad,
                                                 int M, int K, int dorelu) {
  __shared__ bf8 As[256];   // 4 m-tiles x 64 blobs
  __shared__ bf8 Bs[512];   // 8 n-tiles x 64 blobs
  int tid = threadIdx.x;
  int wv = tid >> 6, lane = tid & 63;
  int quad = lane >> 4, m16 = lane & 15;
  int row0 = blockIdx.x * 64;

  int l0 = tid & 63;
  int rA = row0 + (tid >> 6) * 16 + (l0 & 15); if (rA > M - 1) rA = M - 1;
  int nB0 = (tid >> 6) * 16 + (l0 & 15);
  int nB1 = (4 + (tid >> 6)) * 16 + (l0 & 15);
  int cOff = (l0 >> 4) * 8;

  // buffer 0 / buffer 1: named scalars only (no runtime indexing!)
  float4 f0a, f0b, f1a, f1b;
  bf8 h0, h1, b00, b01, b10, b11;

  auto loadT0 = [&](int kb) {
    if (a_bf16) {
      h0 = *reinterpret_cast<const bf8*>((const unsigned short*)Av + (size_t)rA * K + kb + cOff);
    } else {
      const float* p = (const float*)Av + (size_t)rA * K + kb + cOff;
      f0a = *reinterpret_cast<const float4*>(p);
      f0b = *reinterpret_cast<const float4*>(p + 4);
    }
    b00 = *reinterpret_cast<const bf8*>(&Bt[(size_t)nB0 * K + kb + cOff]);
    b01 = *reinterpret_cast<const bf8*>(&Bt[(size_t)nB1 * K + kb + cOff]);
  };
  auto loadT1 = [&](int kb) {
    if (a_bf16) {
      h1 = *reinterpret_cast<const bf8*>((const unsigned short*)Av + (size_t)rA * K + kb + cOff);
    } else {
      const float* p = (const float*)Av + (size_t)rA * K + kb + cOff;
      f1a = *reinterpret_cast<const float4*>(p);
      f1b = *reinterpret_cast<const float4*>(p + 4);
    }
    b10 = *reinterpret_cast<const bf8*>(&Bt[(size_t)nB0 * K + kb + cOff]);
    b11 = *reinterpret_cast<const bf8*>(&Bt[(size_t)nB1 * K + kb + cOff]);
  };
  auto cvt8 = [&](float4 a, float4 b) -> bf8 {
    bf8 v;
    v[0] = (short)f2bf(a.x); v[1] = (short)f2bf(a.y);
    v[2] = (short)f2bf(a.z); v[3] = (short)f2bf(a.w);
    v[4] = (short)f2bf(b.x); v[5] = (short)f2bf(b.y);
    v[6] = (short)f2bf(b.z); v[7] = (short)f2bf(b.w);
    return v;
  };

  f4 acc[8];
#pragma unroll
  for (int b = 0; b < 8; ++b) acc[b] = (f4){0.f, 0.f, 0.f, 0.f};

  loadT0(0);
  loadT1(32);               // K is always >= 64 and a multiple of 64
  for (int kb = 0; kb < K; kb += 64) {
    // ---- step A: consume buffer 0 (tile kb) ----
    __syncthreads();
    As[tid] = a_bf16 ? h0 : cvt8(f0a, f0b);
    Bs[tid] = b00; Bs[tid + 256] = b01;
    __syncthreads();
    if (kb + 64 < K) loadT0(kb + 64);
    {
      bf8 af = As[wv * 64 + lane];
#pragma unroll
      for (int tn = 0; tn < 8; ++tn) {
        bf8 bfm = Bs[tn * 64 + lane];
        acc[tn] = __builtin_amdgcn_mfma_f32_16x16x32_bf16(af, bfm, acc[tn], 0, 0, 0);
      }
    }
    // ---- step B: consume buffer 1 (tile kb+32) ----
    __syncthreads();
    As[tid] = a_bf16 ? h1 : cvt8(f1a, f1b);
    Bs[tid] = b10; Bs[tid + 256] = b11;
    __syncthreads();
    if (kb + 96 < K) loadT1(kb + 96);
    {
      bf8 af = As[wv * 64 + lane];
#pragma unroll
      for (int tn = 0; tn < 8; ++tn) {
        bf8 bfm = Bs[tn * 64 + lane];
        acc[tn] = __builtin_amdgcn_mfma_f32_16x16x32_bf16(af, bfm, acc[tn], 0, 0, 0);
      }
    }
  }

  if (Cp) {
    if (a_src) {
      float aS[8], aD[8];
#pragma unroll
      for (int tn = 0; tn < 4; ++tn) {
        aS[tn]     = a_src[tn * 16 + m16];
        aS[tn + 4] = a_src[64 + tn * 16 + m16];
        aD[tn]     = a_dst[tn * 16 + m16];
        aD[tn + 4] = a_dst[64 + tn * 16 + m16];
      }
#pragma unroll
      for (int r = 0; r < 4; ++r) {
        int row = row0 + wv * 16 + quad * 4 + r;
        float ps0 = 0.f, ps1 = 0.f, pd0 = 0.f, pd1 = 0.f;
#pragma unroll
        for (int tn = 0; tn < 4; ++tn) {
          float v0 = acc[tn][r], v1 = acc[tn + 4][r];
          ps0 = fmaf(v0, aS[tn], ps0);
          ps1 = fmaf(v1, aS[tn + 4], ps1);
          pd0 = fmaf(v0, aD[tn], pd0);
          pd1 = fmaf(v1, aD[tn + 4], pd1);
        }
#pragma unroll
        for (int o = 8; o; o >>= 1) {
          ps0 += __shfl_xor(ps0, o); ps1 += __shfl_xor(ps1, o);
          pd0 += __shfl_xor(pd0, o); pd1 += __shfl_xor(pd1, o);
        }
        if (m16 == 0 && row < M) {
          o_as[2 * row] = ps0; o_as[2 * row + 1] = ps1;
          o_ad[2 * row] = pd0; o_ad[2 * row + 1] = pd1;
        }
      }
    }
#pragma unroll
    for (int tn = 0; tn < 4; ++tn)
#pragma unroll
      for (int r = 0; r < 4; ++r) {
        int row = row0 + wv * 16 + quad * 4 + r;
        if (row < M) {
          unsigned int p = (unsigned int)f2bf(acc[tn][r]) |
                           ((unsigned int)f2bf(acc[tn + 4][r]) << 16);
          Cp[(size_t)row * 64 + tn * 16 + m16] = p;
        }
      }
  } else {
#pragma unroll
    for (int tn = 0; tn < 8; ++tn) {
      float bv = bias ? bias[tn * 16 + m16] : 0.f;
#pragma unroll
      for (int r = 0; r < 4; ++r) {
        int row = row0 + wv * 16 + quad * 4 + r;
        if (row < M) {
          float v = acc[tn][r] + bv;
          if (dorelu) v = fmaxf(v, 0.f);
          Cb[(size_t)row * 128 + tn * 16 + m16] = f2bf(v);
        }
      }
    }
  }
}

// ---------------- graph boundaries (batch is sorted) -------------------------
__global__ void find_starts(const int* __restrict__ batch, int* __restrict__ gstart) {
  int g = threadIdx.x;
  if (g > NGRAPH) return;
  if (g == NGRAPH) { gstart[g] = NNODES; return; }
  int lo = 0, hi = NNODES;
  while (lo < hi) { int mid = (lo + hi) >> 1; if (batch[mid] < g) lo = mid + 1; else hi = mid; }
  gstart[g] = lo;
}

// ======== CSR build, bucketed two-phase (no random global atomics) ==========
__global__ __launch_bounds__(256) void bin_count(const int* __restrict__ edst,
                                                 int* __restrict__ blockHist) {
  __shared__ int hist[NBUCK];
  int t = threadIdx.x, blk = blockIdx.x;
  if (t < NBUCK) hist[t] = 0;
  __syncthreads();
  int e0 = blk * EPB;
#pragma unroll
  for (int it = 0; it < EPB / 256; ++it) {
    int e = e0 + it * 256 + t;
    if (e < NEDGES) atomicAdd(&hist[((unsigned)edst[e]) >> 10], 1);
  }
  __syncthreads();
  if (t < NBUCK) blockHist[blk * NBUCK + t] = hist[t];
}

__global__ __launch_bounds__(512) void colscan(const int* __restrict__ blockHist,
                                               int* __restrict__ blockBaseCol,
                                               int* __restrict__ bucket_total) {
  __shared__ int s[512];
  int b = blockIdx.x, t = threadIdx.x;
  int v = (t < EBLK) ? blockHist[t * NBUCK + b] : 0;
  s[t] = v;
  __syncthreads();
  for (int off = 1; off < 512; off <<= 1) {
    int u = (t >= off) ? s[t - off] : 0;
    __syncthreads();
    s[t] += u;
    __syncthreads();
  }
  if (t < EBLK) blockBaseCol[b * EBLK + t] = s[t] - v;
  if (t == 511) bucket_total[b] = s[511];
}

__global__ __launch_bounds__(128) void bscan(const int* __restrict__ bucket_total,
                                             int* __restrict__ bucket_ptr) {
  __shared__ int s[128];
  int t = threadIdx.x;
  int v = (t < NBUCK) ? bucket_total[t] : 0;
  s[t] = v;
  __syncthreads();
  for (int off = 1; off < 128; off <<= 1) {
    int u = (t >= off) ? s[t - off] : 0;
    __syncthreads();
    s[t] += u;
    __syncthreads();
  }
  if (t < NBUCK) bucket_ptr[t] = s[t] - v;
  if (t == 127) bucket_ptr[NBUCK] = s[127];
}

// staging entry: (dst_local_10bits << 17) | src_17bits  (NNODES < 2^17)
__global__ __launch_bounds__(512) void bin_place(const int* __restrict__ esrc,
                                                 const int* __restrict__ edst,
                                                 const int* __restrict__ blockBaseCol,
                                                 const int* __restrict__ bucket_ptr,
                                                 unsigned* __restrict__ stagingG) {
  __shared__ int hist[NBUCK + 1], lbase[NBUCK + 1], lcur[NBUCK + 1], cbase[NBUCK];
  __shared__ int tmp[128];
  __shared__ uint2 st[EPB];
  int t = threadIdx.x, blk = blockIdx.x;
  if (t < NBUCK + 1) hist[t] = 0;
  __syncthreads();
  int e0 = blk * EPB;
#pragma unroll
  for (int it = 0; it < EPB / 512; ++it) {
    int e = e0 + it * 512 + t;
    int b = NBUCK;
    if (e < NEDGES) b = ((unsigned)edst[e]) >> 10;
    atomicAdd(&hist[b], 1);
  }
  __syncthreads();
  if (t < 128) tmp[t] = (t < NBUCK + 1) ? hist[t] : 0;
  __syncthreads();
  for (int off = 1; off < 128; off <<= 1) {
    int u = 0;
    if (t < 128 && t >= off) u = tmp[t - off];
    __syncthreads();
    if (t < 128) tmp[t] += u;
    __syncthreads();
  }
  if (t < NBUCK + 1) { int ex = tmp[t] - hist[t]; lbase[t] = ex; lcur[t] = ex; }
  if (t < NBUCK) cbase[t] = bucket_ptr[t] + blockBaseCol[t * EBLK + blk];
  __syncthreads();
#pragma unroll
  for (int it = 0; it < EPB / 512; ++it) {
    int e = e0 + it * 512 + t;
    unsigned s = 0, d = 0xFFFFFFFFu;
    if (e < NEDGES) { s = (unsigned)esrc[e]; d = (unsigned)edst[e]; }
    int b = (d == 0xFFFFFFFFu) ? NBUCK : (int)(d >> 10);
    int slot = atomicAdd(&lcur[b], 1);
    st[slot] = make_uint2(s, d);
  }
  __syncthreads();
  for (int i = t; i < EPB; i += 512) {
    uint2 ed = st[i];
    if (ed.y == 0xFFFFFFFFu) continue;
    int b = (int)(ed.y >> 10);
    stagingG[cbase[b] + (i - lbase[b])] = ((ed.y & 1023u) << 17) | ed.x;
  }
}

// fused: per-bucket degree histogram + LDS scan -> row_ptr, then scatter
__global__ __launch_bounds__(1024) void bucket_csr_fused(const unsigned* __restrict__ stagingG,
                                                         const int* __restrict__ bucket_ptr,
                                                         int* __restrict__ row_ptr,
                                                         int* __restrict__ colv) {
  __shared__ int dl[1024];
  __shared__ int cur[1024];
  int b = blockIdx.x, t = threadIdx.x;
  dl[t] = 0;
  __syncthreads();
  int s0 = bucket_ptr[b], s1 = bucket_ptr[b + 1];
  for (int j = s0 + t; j < s1; j += 1024)
    atomicAdd(&dl[stagingG[j] >> 17], 1);
  __syncthreads();
  int myDeg = dl[t];
  for (int off = 1; off < 1024; off <<= 1) {
    int u = (t >= off) ? dl[t - off] : 0;
    __syncthreads();
    dl[t] += u;
    __syncthreads();
  }
  int rp = s0 + dl[t] - myDeg;
  cur[t] = rp;
  int n = (b << 10) + t;
  if (n < NNODES) row_ptr[n] = rp;
  if (n == NNODES - 1) row_ptr[NNODES] = rp + myDeg;
  __syncthreads();
  for (int j = s0 + t; j < s1; j += 1024) {
    unsigned v = stagingG[j];
    int pos = atomicAdd(&cur[v >> 17], 1);
    colv[pos] = (int)(v & 0x1FFFFu);
  }
}

// ---------------- softmax aggregation: XCD-partitioned half-feature waves ----
// R1 post-mortem: VALU cut -20% -> dur flat. Bound by L2-miss traffic of the
// random-src row gather (FETCH 213MB vs 32MB streaming; 3.4 TB/s path).
// Mechanism fix: partition the 256B feature row into two 128B halves and pin
// each half to one XCD group (blockIdx%8 round-robins across the 8 XCDs ->
// %8<4 = XCDs 0-3 own cols[0,32), %8>=4 = XCDs 4-7 own cols[32,64)). Each
// XCD's gather working set drops 25.6MB -> 12.8MB -> capacity hit rate up.
// A wave serves TWO nodes on one half: lanes 0-31 node A, lanes 32-63 node B;
// one load instruction gathers one edge-row-half of each node (2x128B).
// Phase 1 (weights/denominator) is duplicated per half: a_s is 800KB ->
// L2-resident in both XCD groups; only colv re-read (+6.4MB) is real cost.
__global__ __launch_bounds__(256) void aggregate(const unsigned int* __restrict__ hwb,
                                                 const float* __restrict__ a_s,
                                                 const float* __restrict__ a_d,
                                                 const int* __restrict__ row_ptr,
                                                 const int* __restrict__ colv,
                                                 const float* __restrict__ bias,
                                                 unsigned short* __restrict__ out) {
  int b = blockIdx.x;
  int half = (b & 7) >> 2;               // XCD 0-3 -> half 0, XCD 4-7 -> half 1
  int slot = (b >> 3) * 4 + (b & 3);     // [0, 12500)
  int tid = threadIdx.x;
  int wv = tid >> 6, lane = tid & 63;
  int g = lane >> 5, c = lane & 31;      // g: which node, c: col within half
  int n = slot * 8 + wv * 2 + g;         // node id < 100000 (12500*8 exact)
  int col = half * 32 + c;               // u32 col in [0,64)

  float ad0 = a_d[2 * n], ad1 = a_d[2 * n + 1];
  int start = row_ptr[n], end = row_ptr[n + 1];
  int deg = end - start;
  float ws0 = __expf(lrelu(a_s[2 * n] + ad0));      // self edge
  float ws1 = __expf(lrelu(a_s[2 * n + 1] + ad1));

  int sl = 0; float w0l = 0.f, w1l = 0.f;
  if (c < deg) {
    sl = colv[start + c];
    float2 av = *reinterpret_cast<const float2*>(&a_s[2 * sl]);
    w0l = __expf(lrelu(av.x + ad0));
    w1l = __expf(lrelu(av.y + ad1));
  }
  // denominator: reduce over the 32 lanes of this node's group
  float d0 = w0l, d1 = w1l;
  for (int o = 16; o; o >>= 1) { d0 += __shfl_xor(d0, o); d1 += __shfl_xor(d1, o); }
  float den0 = d0 + ws0, den1 = d1 + ws1;

  unsigned int ps = hwb[(size_t)n * 64 + col];
  float acc0 = ws0 * bf_lo(ps), acc1 = ws1 * bf_hi(ps);

  int dmin = deg < 32 ? deg : 32;
  int tripA = __builtin_amdgcn_readlane(dmin, 0);
  int tripB = __builtin_amdgcn_readlane(dmin, 32);
  int trip = tripA > tripB ? tripA : tripB;   // wave-uniform; short side loads
                                              // row 0 (hot) with w=0

#define GSTEP(T)                                                               \
  {                                                                            \
    int sA = __builtin_amdgcn_readlane(sl, (T));                               \
    int sB = __builtin_amdgcn_readlane(sl, 32 + (T));                          \
    float uA = __uint_as_float(__builtin_amdgcn_readlane(__float_as_uint(w0l), (T)));      \
    float vA = __uint_as_float(__builtin_amdgcn_readlane(__float_as_uint(w1l), (T)));      \
    float uB = __uint_as_float(__builtin_amdgcn_readlane(__float_as_uint(w0l), 32 + (T))); \
    float vB = __uint_as_float(__builtin_amdgcn_readlane(__float_as_uint(w1l), 32 + (T))); \
    int s = g ? sB : sA;                                                       \
    float u = g ? uB : uA;                                                     \
    float v = g ? vB : vA;                                                     \
    unsigned q = hwb[(size_t)s * 64 + col];                                    \
    acc0 = fmaf(u, bf_lo(q), acc0);                                            \
    acc1 = fmaf(v, bf_hi(q), acc1);                                            \
  }

  int t = 0;
  for (; t + 4 <= trip; t += 4) {
    GSTEP(t); GSTEP(t + 1); GSTEP(t + 2); GSTEP(t + 3);
  }
  for (; t < trip; ++t) { GSTEP(t); }
#undef GSTEP

  // rare overflow path (deg > 32), divergent between the two half-groups
  for (int j = start + 32; j < end; ++j) {
    int s = colv[j];
    float2 av = *reinterpret_cast<const float2*>(&a_s[2 * s]);
    float w0 = __expf(lrelu(av.x + ad0));
    float w1 = __expf(lrelu(av.y + ad1));
    den0 += w0; den1 += w1;
    unsigned q = hwb[(size_t)s * 64 + col];
    acc0 = fmaf(w0, bf_lo(q), acc0);
    acc1 = fmaf(w1, bf_hi(q), acc1);
  }

  float r0 = fast_rcp(den0), r1 = fast_rcp(den1);
  float o0 = fmaxf(acc0 * r0 + bias[col], 0.f);
  float o1 = fmaxf(acc1 * r1 + bias[64 + col], 0.f);
  unsigned pk = cvt_pk_bf16(o0, o1);
  out[(size_t)n * 128 + col]      = (unsigned short)pk;
  out[(size_t)n * 128 + 64 + col] = (unsigned short)(pk >> 16);
}

// ---------------- per-graph pooling, node-parallel (bf16 input) --------------
#define SEG_CHUNK 128
__global__ __launch_bounds__(128) void seg_sum_fast(const unsigned short* __restrict__ h,
                                                    const int* __restrict__ batch,
                                                    const int* __restrict__ gstart,
                                                    float* __restrict__ reprs) {
  int n0 = blockIdx.x * SEG_CHUNK;
  if (n0 >= NNODES) return;
  int nend = n0 + SEG_CHUNK; if (nend > NNODES) nend = NNODES;
  int tid = threadIdx.x;
  int r = n0;
  while (r < nend) {
    int g = batch[r];
    int segend = gstart[g + 1]; if (segend > nend) segend = nend;
    float a0 = 0.f, a1 = 0.f, a2 = 0.f, a3 = 0.f;
    for (; r + 3 < segend; r += 4) {
      a0 += bf2f(h[(size_t)r * 128 + tid]);
      a1 += bf2f(h[(size_t)(r + 1) * 128 + tid]);
      a2 += bf2f(h[(size_t)(r + 2) * 128 + tid]);
      a3 += bf2f(h[(size_t)(r + 3) * 128 + tid]);
    }
    for (; r < segend; ++r) a0 += bf2f(h[(size_t)r * 128 + tid]);
    atomicAdd(&reprs[g * 128 + tid], (a0 + a1) + (a2 + a3));
  }
}

// ---------------- head MLP + log_softmax -------------------------------------
__global__ __launch_bounds__(128) void head_kernel(const float* __restrict__ reprs,
                                                   const float* __restrict__ pw1,
                                                   const float* __restrict__ pb1,
                                                   const float* __restrict__ pw2,
                                                   const float* __restrict__ pb2,
                                                   float* __restrict__ out) {
  __shared__ float r[128], t1[128], z[NCLS];
  int g = blockIdx.x, tid = threadIdx.x;
  r[tid] = reprs[g * 128 + tid];
  __syncthreads();
  float acc = pb1[tid];
  for (int k = 0; k < 128; ++k) acc = fmaf(r[k], pw1[k * 128 + tid], acc);
  t1[tid] = fmaxf(acc, 0.f);
  __syncthreads();
  if (tid < NCLS) {
    float zz = pb2[tid];
    for (int k = 0; k < 128; ++k) zz = fmaf(t1[k], pw2[k * NCLS + tid], zz);
    z[tid] = zz;
  }
  __syncthreads();
  if (tid == 0) {
    float mx = -1e30f;
    for (int c = 0; c < NCLS; ++c) mx = fmaxf(mx, z[c]);
    float s = 0.f;
    for (int c = 0; c < NCLS; ++c) s += expf(z[c] - mx);
    float ls = logf(s) + mx;
    for (int c = 0; c < NCLS; ++c) out[g * NCLS + c] = z[c] - ls;
  }
}

extern "C" void kernel_launch(void* const* d_in, const int* in_sizes, int n_in,
                              void* d_out, int out_size, void* d_ws, size_t ws_size,
                              hipStream_t stream) {
  const float* x     = (const float*)d_in[0];
  const int*   eidx  = (const int*)d_in[1];
  const int*   batch = (const int*)d_in[2];
  const float* pre_w = (const float*)d_in[3];
  const float* pre_b = (const float*)d_in[4];
  const float* w1    = (const float*)d_in[5];
  const float* asrc1 = (const float*)d_in[6];
  const float* adst1 = (const float*)d_in[7];
  const float* b1    = (const float*)d_in[8];
  const float* w2    = (const float*)d_in[9];
  const float* asrc2 = (const float*)d_in[10];
  const float* adst2 = (const float*)d_in[11];
  const float* b2    = (const float*)d_in[12];
  const float* pw1   = (const float*)d_in[13];
  const float* pb1   = (const float*)d_in[14];
  const float* pw2   = (const float*)d_in[15];
  const float* pb2   = (const float*)d_in[16];
  float* out = (float*)d_out;

  const int* esrc = eidx;
  const int* edst = eidx + NEDGES;

  char* wsp = (char*)d_ws;
  size_t off = 0;
  auto alloc = [&](size_t bytes) -> void* {
    void* p = wsp + off;
    off += (bytes + 255) & ~(size_t)255;
    return p;
  };
  unsigned short* hb = (unsigned short*)alloc((size_t)NNODES * 128 * 2);
  unsigned int* hwb  = (unsigned int*)alloc((size_t)NNODES * 64 * 4);
  float* a_s         = (float*)alloc((size_t)NNODES * 2 * 4);
  float* a_d         = (float*)alloc((size_t)NNODES * 2 * 4);
  float* reprs       = (float*)alloc((size_t)NGRAPH * 128 * 4);
  int* gstart        = (int*)alloc((NGRAPH + 1) * 4);
  int* row_ptr       = (int*)alloc(((size_t)NNODES + 1) * 4);
  int* colv          = (int*)alloc((size_t)NEDGES * 4);
  unsigned short* wt_pre = (unsigned short*)alloc((size_t)128 * FIN * 2);
  unsigned short* wt1    = (unsigned short*)alloc((size_t)128 * HDIM * 2);
  unsigned short* wt2    = (unsigned short*)alloc((size_t)128 * HDIM * 2);
  int* blockHist     = (int*)alloc((size_t)EBLK * NBUCK * 4);
  int* blockBaseCol  = (int*)alloc((size_t)NBUCK * EBLK * 4);
  int* bucket_total  = (int*)alloc(NBUCK * 4);
  int* bucket_ptr    = (int*)alloc((NBUCK + 1) * 4);
  unsigned* stagingG = (unsigned*)alloc((size_t)NEDGES * 4);

  int ab = (NNODES / 8) * 2;       // aggregate: 8 node-halves per 256-thr block
  int sb = (NNODES + SEG_CHUNK - 1) / SEG_CHUNK;
  int gb = (NNODES + 63) / 64;     // 1563 GEMM blocks (64-row tiles)

  // one-shot weight conversion (bf16, transposed)
  convert_transpose<<<(FIN * 128 + 255) / 256, 256, 0, stream>>>(pre_w, wt_pre, FIN);
  convert_transpose<<<(HDIM * 128 + 255) / 256, 256, 0, stream>>>(w1, wt1, HDIM);
  convert_transpose<<<(HDIM * 128 + 255) / 256, 256, 0, stream>>>(w2, wt2, HDIM);

  // graph boundaries + zeroed pooling accumulator
  hipMemsetAsync(reprs, 0, (size_t)NGRAPH * 128 * 4, stream);
  find_starts<<<1, 256, 0, stream>>>(batch, gstart);

  // bucketed CSR build (packed 4B staging; fused deg-scan + scatter)
  bin_count<<<EBLK, 256, 0, stream>>>(edst, blockHist);
  colscan<<<NBUCK, 512, 0, stream>>>(blockHist, blockBaseCol, bucket_total);
  bscan<<<1, 128, 0, stream>>>(bucket_total, bucket_ptr);
  bin_place<<<EBLK, 512, 0, stream>>>(esrc, edst, blockBaseCol, bucket_ptr, stagingG);
  bucket_csr_fused<<<NBUCK, 1024, 0, stream>>>(stagingG, bucket_ptr, row_ptr, colv);

  // pre layer: h0 = relu(x @ pre_w + pre_b)  (bf16 h)
  gemm_mfma<<<gb, 256, 0, stream>>>(x, 0, wt_pre, pre_b, hb, nullptr,
                                    nullptr, nullptr, nullptr, nullptr, NNODES, FIN, 1);
  seg_sum_fast<<<sb, 128, 0, stream>>>(hb, batch, gstart, reprs);

  // GAT layer 1 (bf16 A; alpha fused into GEMM epilogue)
  gemm_mfma<<<gb, 256, 0, stream>>>(hb, 1, wt1, nullptr, nullptr, hwb,
                                    asrc1, adst1, a_s, a_d, NNODES, HDIM, 0);
  aggregate<<<ab, 256, 0, stream>>>(hwb, a_s, a_d, row_ptr, colv, b1, hb);
  seg_sum_fast<<<sb, 128, 0, stream>>>(hb, batch, gstart, reprs);

  // GAT layer 2
  gemm_mfma<<<gb, 256, 0, stream>>>(hb, 1, wt2, nullptr, nullptr, hwb,
                                    asrc2, adst2, a_s, a_d, NNODES, HDIM, 0);
  aggregate<<<ab, 256, 0, stream>>>(hwb, a_s, a_d, row_ptr, colv, b2, hb);
  seg_sum_fast<<<sb, 128, 0, stream>>>(hb, batch, gstart, reprs);

  // head
  head_kernel<<<NGRAPH, 128, 0, stream>>>(reprs, pw1, pb1, pw2, pb2, out);
}

// Round 3
// 473.844 us; speedup vs baseline: 1.1774x; 1.1774x over previous
//
#include <hip/hip_runtime.h>
#include <hip/hip_bf16.h>
#include <math.h>

#define NNODES 100000
#define NEDGES 1600000
#define FIN 256
#define HDIM 128
#define NGRAPH 128
#define NCLS 10
#define NEG 0.2f

#define NBUCK 98            // buckets of 1024 dst nodes
#define EPB 4096            // edges per bin_place block
#define EBLK ((NEDGES + EPB - 1) / EPB)   // 391

typedef short bf8 __attribute__((ext_vector_type(8)));
typedef float f4 __attribute__((ext_vector_type(4)));

__device__ __forceinline__ float lrelu(float x) { return x > 0.f ? x : NEG * x; }

__device__ __forceinline__ unsigned short f2bf(float f) {
  union { float f; unsigned int u; } v; v.f = f;
  unsigned int r = v.u + 0x7fffu + ((v.u >> 16) & 1u);   // round-nearest-even
  return (unsigned short)(r >> 16);
}
__device__ __forceinline__ float bf2f(unsigned short u) {
  union { unsigned int u; float f; } v; v.u = ((unsigned int)u) << 16; return v.f;
}
__device__ __forceinline__ float fast_rcp(float x) {
  float r;
  asm("v_rcp_f32 %0, %1" : "=v"(r) : "v"(x));
  return r;
}
__device__ __forceinline__ unsigned cvt_pk_bf16(float lo, float hi) {
  unsigned r;
  asm("v_cvt_pk_bf16_f32 %0, %1, %2" : "=v"(r) : "v"(lo), "v"(hi));
  return r;
}
// fp8 e4m3 (OCP, gfx950 native) pack/unpack: value payload for the gather.
__device__ __forceinline__ unsigned short pk_fp8(float a, float b) {
  return (unsigned short)__builtin_amdgcn_cvt_pk_fp8_f32(a, b, 0, false);
}
__device__ __forceinline__ float fp8_lo(unsigned p) {
  return __builtin_amdgcn_cvt_f32_fp8(p, 0);
}
__device__ __forceinline__ float fp8_hi(unsigned p) {
  return __builtin_amdgcn_cvt_f32_fp8(p, 1);
}

// ---------------- one-shot weight convert+transpose: w[K][128] -> wt[128][K] -
__global__ __launch_bounds__(256) void convert_transpose(const float* __restrict__ w,
                                                         unsigned short* __restrict__ wt,
                                                         int K) {
  int i = blockIdx.x * 256 + threadIdx.x;
  if (i >= K * 128) return;
  int k = i >> 7, n = i & 127;
  wt[n * K + k] = f2bf(w[(size_t)k * 128 + n]);
}

// ---------------- MFMA GEMM: 64-row tiles, depth-2 prefetch (STATIC buffers) -
// Block tile 64 x 128 (grid ~1563 -> ~6 blocks/CU). Wave w: m-tile w (16 rows).
// K-loop unrolled x2 so buffer selection is compile-time (runtime-indexed
// register arrays spill to scratch -- R11 lesson: 110MB scratch writes).
// Cp output (GAT layers) is now fp8 e4m3 pairs (head0,head1) -- 128B/row;
// alpha epilogue (a_s/a_d) still computed from the f32 accumulator -> exact.
__global__ __launch_bounds__(256) void gemm_mfma(const void* __restrict__ Av,
                                                 int a_bf16,
                                                 const unsigned short* __restrict__ Bt,
                                                 const float* __restrict__ bias,
                                                 unsigned short* __restrict__ Cb,
                                                 unsigned short* __restrict__ Cp,
                                                 const float* __restrict__ a_src,
                                                 const float* __restrict__ a_dst,
                                                 float* __restrict__ o_as,
                                                 float* __restrict__ o_ad,
                                                 int M, int K, int dorelu) {
  __shared__ bf8 As[256];   // 4 m-tiles x 64 blobs
  __shared__ bf8 Bs[512];   // 8 n-tiles x 64 blobs
  int tid = threadIdx.x;
  int wv = tid >> 6, lane = tid & 63;
  int quad = lane >> 4, m16 = lane & 15;
  int row0 = blockIdx.x * 64;

  int l0 = tid & 63;
  int rA = row0 + (tid >> 6) * 16 + (l0 & 15); if (rA > M - 1) rA = M - 1;
  int nB0 = (tid >> 6) * 16 + (l0 & 15);
  int nB1 = (4 + (tid >> 6)) * 16 + (l0 & 15);
  int cOff = (l0 >> 4) * 8;

  // buffer 0 / buffer 1: named scalars only (no runtime indexing!)
  float4 f0a, f0b, f1a, f1b;
  bf8 h0, h1, b00, b01, b10, b11;

  auto loadT0 = [&](int kb) {
    if (a_bf16) {
      h0 = *reinterpret_cast<const bf8*>((const unsigned short*)Av + (size_t)rA * K + kb + cOff);
    } else {
      const float* p = (const float*)Av + (size_t)rA * K + kb + cOff;
      f0a = *reinterpret_cast<const float4*>(p);
      f0b = *reinterpret_cast<const float4*>(p + 4);
    }
    b00 = *reinterpret_cast<const bf8*>(&Bt[(size_t)nB0 * K + kb + cOff]);
    b01 = *reinterpret_cast<const bf8*>(&Bt[(size_t)nB1 * K + kb + cOff]);
  };
  auto loadT1 = [&](int kb) {
    if (a_bf16) {
      h1 = *reinterpret_cast<const bf8*>((const unsigned short*)Av + (size_t)rA * K + kb + cOff);
    } else {
      const float* p = (const float*)Av + (size_t)rA * K + kb + cOff;
      f1a = *reinterpret_cast<const float4*>(p);
      f1b = *reinterpret_cast<const float4*>(p + 4);
    }
    b10 = *reinterpret_cast<const bf8*>(&Bt[(size_t)nB0 * K + kb + cOff]);
    b11 = *reinterpret_cast<const bf8*>(&Bt[(size_t)nB1 * K + kb + cOff]);
  };
  auto cvt8 = [&](float4 a, float4 b) -> bf8 {
    bf8 v;
    v[0] = (short)f2bf(a.x); v[1] = (short)f2bf(a.y);
    v[2] = (short)f2bf(a.z); v[3] = (short)f2bf(a.w);
    v[4] = (short)f2bf(b.x); v[5] = (short)f2bf(b.y);
    v[6] = (short)f2bf(b.z); v[7] = (short)f2bf(b.w);
    return v;
  };

  f4 acc[8];
#pragma unroll
  for (int b = 0; b < 8; ++b) acc[b] = (f4){0.f, 0.f, 0.f, 0.f};

  loadT0(0);
  loadT1(32);               // K is always >= 64 and a multiple of 64
  for (int kb = 0; kb < K; kb += 64) {
    // ---- step A: consume buffer 0 (tile kb) ----
    __syncthreads();
    As[tid] = a_bf16 ? h0 : cvt8(f0a, f0b);
    Bs[tid] = b00; Bs[tid + 256] = b01;
    __syncthreads();
    if (kb + 64 < K) loadT0(kb + 64);
    {
      bf8 af = As[wv * 64 + lane];
#pragma unroll
      for (int tn = 0; tn < 8; ++tn) {
        bf8 bfm = Bs[tn * 64 + lane];
        acc[tn] = __builtin_amdgcn_mfma_f32_16x16x32_bf16(af, bfm, acc[tn], 0, 0, 0);
      }
    }
    // ---- step B: consume buffer 1 (tile kb+32) ----
    __syncthreads();
    As[tid] = a_bf16 ? h1 : cvt8(f1a, f1b);
    Bs[tid] = b10; Bs[tid + 256] = b11;
    __syncthreads();
    if (kb + 96 < K) loadT1(kb + 96);
    {
      bf8 af = As[wv * 64 + lane];
#pragma unroll
      for (int tn = 0; tn < 8; ++tn) {
        bf8 bfm = Bs[tn * 64 + lane];
        acc[tn] = __builtin_amdgcn_mfma_f32_16x16x32_bf16(af, bfm, acc[tn], 0, 0, 0);
      }
    }
  }

  if (Cp) {
    if (a_src) {
      float aS[8], aD[8];
#pragma unroll
      for (int tn = 0; tn < 4; ++tn) {
        aS[tn]     = a_src[tn * 16 + m16];
        aS[tn + 4] = a_src[64 + tn * 16 + m16];
        aD[tn]     = a_dst[tn * 16 + m16];
        aD[tn + 4] = a_dst[64 + tn * 16 + m16];
      }
#pragma unroll
      for (int r = 0; r < 4; ++r) {
        int row = row0 + wv * 16 + quad * 4 + r;
        float ps0 = 0.f, ps1 = 0.f, pd0 = 0.f, pd1 = 0.f;
#pragma unroll
        for (int tn = 0; tn < 4; ++tn) {
          float v0 = acc[tn][r], v1 = acc[tn + 4][r];
          ps0 = fmaf(v0, aS[tn], ps0);
          ps1 = fmaf(v1, aS[tn + 4], ps1);
          pd0 = fmaf(v0, aD[tn], pd0);
          pd1 = fmaf(v1, aD[tn + 4], pd1);
        }
#pragma unroll
        for (int o = 8; o; o >>= 1) {
          ps0 += __shfl_xor(ps0, o); ps1 += __shfl_xor(ps1, o);
          pd0 += __shfl_xor(pd0, o); pd1 += __shfl_xor(pd1, o);
        }
        if (m16 == 0 && row < M) {
          o_as[2 * row] = ps0; o_as[2 * row + 1] = ps1;
          o_ad[2 * row] = pd0; o_ad[2 * row + 1] = pd1;
        }
      }
    }
#pragma unroll
    for (int tn = 0; tn < 4; ++tn)
#pragma unroll
      for (int r = 0; r < 4; ++r) {
        int row = row0 + wv * 16 + quad * 4 + r;
        if (row < M) {
          Cp[(size_t)row * 64 + tn * 16 + m16] = pk_fp8(acc[tn][r], acc[tn + 4][r]);
        }
      }
  } else {
#pragma unroll
    for (int tn = 0; tn < 8; ++tn) {
      float bv = bias ? bias[tn * 16 + m16] : 0.f;
#pragma unroll
      for (int r = 0; r < 4; ++r) {
        int row = row0 + wv * 16 + quad * 4 + r;
        if (row < M) {
          float v = acc[tn][r] + bv;
          if (dorelu) v = fmaxf(v, 0.f);
          Cb[(size_t)row * 128 + tn * 16 + m16] = f2bf(v);
        }
      }
    }
  }
}

// ---------------- graph boundaries (batch is sorted) -------------------------
__global__ void find_starts(const int* __restrict__ batch, int* __restrict__ gstart) {
  int g = threadIdx.x;
  if (g > NGRAPH) return;
  if (g == NGRAPH) { gstart[g] = NNODES; return; }
  int lo = 0, hi = NNODES;
  while (lo < hi) { int mid = (lo + hi) >> 1; if (batch[mid] < g) lo = mid + 1; else hi = mid; }
  gstart[g] = lo;
}

// ======== CSR build, bucketed two-phase (no random global atomics) ==========
__global__ __launch_bounds__(256) void bin_count(const int* __restrict__ edst,
                                                 int* __restrict__ blockHist) {
  __shared__ int hist[NBUCK];
  int t = threadIdx.x, blk = blockIdx.x;
  if (t < NBUCK) hist[t] = 0;
  __syncthreads();
  int e0 = blk * EPB;
#pragma unroll
  for (int it = 0; it < EPB / 256; ++it) {
    int e = e0 + it * 256 + t;
    if (e < NEDGES) atomicAdd(&hist[((unsigned)edst[e]) >> 10], 1);
  }
  __syncthreads();
  if (t < NBUCK) blockHist[blk * NBUCK + t] = hist[t];
}

__global__ __launch_bounds__(512) void colscan(const int* __restrict__ blockHist,
                                               int* __restrict__ blockBaseCol,
                                               int* __restrict__ bucket_total) {
  __shared__ int s[512];
  int b = blockIdx.x, t = threadIdx.x;
  int v = (t < EBLK) ? blockHist[t * NBUCK + b] : 0;
  s[t] = v;
  __syncthreads();
  for (int off = 1; off < 512; off <<= 1) {
    int u = (t >= off) ? s[t - off] : 0;
    __syncthreads();
    s[t] += u;
    __syncthreads();
  }
  if (t < EBLK) blockBaseCol[b * EBLK + t] = s[t] - v;
  if (t == 511) bucket_total[b] = s[511];
}

__global__ __launch_bounds__(128) void bscan(const int* __restrict__ bucket_total,
                                             int* __restrict__ bucket_ptr) {
  __shared__ int s[128];
  int t = threadIdx.x;
  int v = (t < NBUCK) ? bucket_total[t] : 0;
  s[t] = v;
  __syncthreads();
  for (int off = 1; off < 128; off <<= 1) {
    int u = (t >= off) ? s[t - off] : 0;
    __syncthreads();
    s[t] += u;
    __syncthreads();
  }
  if (t < NBUCK) bucket_ptr[t] = s[t] - v;
  if (t == 127) bucket_ptr[NBUCK] = s[127];
}

// staging entry: (dst_local_10bits << 17) | src_17bits  (NNODES < 2^17)
__global__ __launch_bounds__(512) void bin_place(const int* __restrict__ esrc,
                                                 const int* __restrict__ edst,
                                                 const int* __restrict__ blockBaseCol,
                                                 const int* __restrict__ bucket_ptr,
                                                 unsigned* __restrict__ stagingG) {
  __shared__ int hist[NBUCK + 1], lbase[NBUCK + 1], lcur[NBUCK + 1], cbase[NBUCK];
  __shared__ int tmp[128];
  __shared__ uint2 st[EPB];
  int t = threadIdx.x, blk = blockIdx.x;
  if (t < NBUCK + 1) hist[t] = 0;
  __syncthreads();
  int e0 = blk * EPB;
#pragma unroll
  for (int it = 0; it < EPB / 512; ++it) {
    int e = e0 + it * 512 + t;
    int b = NBUCK;
    if (e < NEDGES) b = ((unsigned)edst[e]) >> 10;
    atomicAdd(&hist[b], 1);
  }
  __syncthreads();
  if (t < 128) tmp[t] = (t < NBUCK + 1) ? hist[t] : 0;
  __syncthreads();
  for (int off = 1; off < 128; off <<= 1) {
    int u = 0;
    if (t < 128 && t >= off) u = tmp[t - off];
    __syncthreads();
    if (t < 128) tmp[t] += u;
    __syncthreads();
  }
  if (t < NBUCK + 1) { int ex = tmp[t] - hist[t]; lbase[t] = ex; lcur[t] = ex; }
  if (t < NBUCK) cbase[t] = bucket_ptr[t] + blockBaseCol[t * EBLK + blk];
  __syncthreads();
#pragma unroll
  for (int it = 0; it < EPB / 512; ++it) {
    int e = e0 + it * 512 + t;
    unsigned s = 0, d = 0xFFFFFFFFu;
    if (e < NEDGES) { s = (unsigned)esrc[e]; d = (unsigned)edst[e]; }
    int b = (d == 0xFFFFFFFFu) ? NBUCK : (int)(d >> 10);
    int slot = atomicAdd(&lcur[b], 1);
    st[slot] = make_uint2(s, d);
  }
  __syncthreads();
  for (int i = t; i < EPB; i += 512) {
    uint2 ed = st[i];
    if (ed.y == 0xFFFFFFFFu) continue;
    int b = (int)(ed.y >> 10);
    stagingG[cbase[b] + (i - lbase[b])] = ((ed.y & 1023u) << 17) | ed.x;
  }
}

// fused: per-bucket degree histogram + LDS scan -> row_ptr, then scatter
__global__ __launch_bounds__(1024) void bucket_csr_fused(const unsigned* __restrict__ stagingG,
                                                         const int* __restrict__ bucket_ptr,
                                                         int* __restrict__ row_ptr,
                                                         int* __restrict__ colv) {
  __shared__ int dl[1024];
  __shared__ int cur[1024];
  int b = blockIdx.x, t = threadIdx.x;
  dl[t] = 0;
  __syncthreads();
  int s0 = bucket_ptr[b], s1 = bucket_ptr[b + 1];
  for (int j = s0 + t; j < s1; j += 1024)
    atomicAdd(&dl[stagingG[j] >> 17], 1);
  __syncthreads();
  int myDeg = dl[t];
  for (int off = 1; off < 1024; off <<= 1) {
    int u = (t >= off) ? dl[t - off] : 0;
    __syncthreads();
    dl[t] += u;
    __syncthreads();
  }
  int rp = s0 + dl[t] - myDeg;
  cur[t] = rp;
  int n = (b << 10) + t;
  if (n < NNODES) row_ptr[n] = rp;
  if (n == NNODES - 1) row_ptr[NNODES] = rp + myDeg;
  __syncthreads();
  for (int j = s0 + t; j < s1; j += 1024) {
    unsigned v = stagingG[j];
    int pos = atomicAdd(&cur[v >> 17], 1);
    colv[pos] = (int)(v & 0x1FFFFu);
  }
}

// ---------------- softmax aggregation: one wave per dst node -----------------
// R1 structure (proven lowest-VALU), with the value payload in fp8 e4m3:
// row = 64 lanes x u16 (fp8 head0 | fp8 head1 <<8) = 128B (was 256B bf16).
// R1/R2 established the kernel is bound by random-gather traffic (~3.4 TB/s
// effective); halving payload bytes at identical instruction count is the
// only lever that attacks it. Softmax weights come from exact f32 a_s/a_d.
__global__ __launch_bounds__(256) void aggregate(const unsigned short* __restrict__ hwb,
                                                 const float* __restrict__ a_s,
                                                 const float* __restrict__ a_d,
                                                 const int* __restrict__ row_ptr,
                                                 const int* __restrict__ colv,
                                                 const float* __restrict__ bias,
                                                 unsigned short* __restrict__ out) {
  int i = (blockIdx.x * 256 + threadIdx.x) >> 6;
  int lane = threadIdx.x & 63;
  if (i >= NNODES) return;
  i = __builtin_amdgcn_readfirstlane(i);

  float ad0 = a_d[2 * i], ad1 = a_d[2 * i + 1];
  int start = row_ptr[i], end = row_ptr[i + 1];
  int deg = end - start;
  float ws0 = __expf(lrelu(a_s[2 * i] + ad0));      // self edge
  float ws1 = __expf(lrelu(a_s[2 * i + 1] + ad1));

  int sl = 0; float w0l = 0.f, w1l = 0.f;
  if (lane < deg) {
    sl = colv[start + lane];
    float2 av = *reinterpret_cast<const float2*>(&a_s[2 * sl]);
    w0l = __expf(lrelu(av.x + ad0));
    w1l = __expf(lrelu(av.y + ad1));
  }
  float d0 = w0l, d1 = w1l;
  for (int o = 32; o; o >>= 1) { d0 += __shfl_xor(d0, o); d1 += __shfl_xor(d1, o); }
  float den0 = d0 + ws0, den1 = d1 + ws1;

  unsigned ps = hwb[(size_t)i * 64 + lane];
  float acc0 = ws0 * fp8_lo(ps), acc1 = ws1 * fp8_hi(ps);

  int dmin = deg < 64 ? deg : 64;
  int t = 0;
  for (; t + 4 <= dmin; t += 4) {
    int s0 = __builtin_amdgcn_readlane(sl, t);
    int s1 = __builtin_amdgcn_readlane(sl, t + 1);
    int s2 = __builtin_amdgcn_readlane(sl, t + 2);
    int s3 = __builtin_amdgcn_readlane(sl, t + 3);
    unsigned q0 = hwb[(size_t)s0 * 64 + lane];
    unsigned q1 = hwb[(size_t)s1 * 64 + lane];
    unsigned q2 = hwb[(size_t)s2 * 64 + lane];
    unsigned q3 = hwb[(size_t)s3 * 64 + lane];
    float u0 = __uint_as_float(__builtin_amdgcn_readlane(__float_as_uint(w0l), t));
    float v0 = __uint_as_float(__builtin_amdgcn_readlane(__float_as_uint(w1l), t));
    float u1 = __uint_as_float(__builtin_amdgcn_readlane(__float_as_uint(w0l), t + 1));
    float v1 = __uint_as_float(__builtin_amdgcn_readlane(__float_as_uint(w1l), t + 1));
    float u2 = __uint_as_float(__builtin_amdgcn_readlane(__float_as_uint(w0l), t + 2));
    float v2 = __uint_as_float(__builtin_amdgcn_readlane(__float_as_uint(w1l), t + 2));
    float u3 = __uint_as_float(__builtin_amdgcn_readlane(__float_as_uint(w0l), t + 3));
    float v3 = __uint_as_float(__builtin_amdgcn_readlane(__float_as_uint(w1l), t + 3));
    acc0 = fmaf(u0, fp8_lo(q0), acc0); acc1 = fmaf(v0, fp8_hi(q0), acc1);
    acc0 = fmaf(u1, fp8_lo(q1), acc0); acc1 = fmaf(v1, fp8_hi(q1), acc1);
    acc0 = fmaf(u2, fp8_lo(q2), acc0); acc1 = fmaf(v2, fp8_hi(q2), acc1);
    acc0 = fmaf(u3, fp8_lo(q3), acc0); acc1 = fmaf(v3, fp8_hi(q3), acc1);
  }
  for (; t < dmin; ++t) {
    int s = __builtin_amdgcn_readlane(sl, t);
    float u = __uint_as_float(__builtin_amdgcn_readlane(__float_as_uint(w0l), t));
    float v = __uint_as_float(__builtin_amdgcn_readlane(__float_as_uint(w1l), t));
    unsigned q = hwb[(size_t)s * 64 + lane];
    acc0 = fmaf(u, fp8_lo(q), acc0);
    acc1 = fmaf(v, fp8_hi(q), acc1);
  }
  for (int j = start + 64; j < end; ++j) {   // rare overflow path (deg > 64)
    int s = colv[j];
    float2 av = *reinterpret_cast<const float2*>(&a_s[2 * s]);
    float w0 = __expf(lrelu(av.x + ad0));
    float w1 = __expf(lrelu(av.y + ad1));
    den0 += w0; den1 += w1;
    unsigned q = hwb[(size_t)s * 64 + lane];
    acc0 = fmaf(w0, fp8_lo(q), acc0);
    acc1 = fmaf(w1, fp8_hi(q), acc1);
  }

  float r0 = fast_rcp(den0), r1 = fast_rcp(den1);
  float o0 = fmaxf(acc0 * r0 + bias[lane], 0.f);
  float o1 = fmaxf(acc1 * r1 + bias[64 + lane], 0.f);
  unsigned pk = cvt_pk_bf16(o0, o1);
  out[(size_t)i * 128 + lane]      = (unsigned short)pk;
  out[(size_t)i * 128 + 64 + lane] = (unsigned short)(pk >> 16);
}

// ---------------- per-graph pooling, node-parallel (bf16 input) --------------
#define SEG_CHUNK 128
__global__ __launch_bounds__(128) void seg_sum_fast(const unsigned short* __restrict__ h,
                                                    const int* __restrict__ batch,
                                                    const int* __restrict__ gstart,
                                                    float* __restrict__ reprs) {
  int n0 = blockIdx.x * SEG_CHUNK;
  if (n0 >= NNODES) return;
  int nend = n0 + SEG_CHUNK; if (nend > NNODES) nend = NNODES;
  int tid = threadIdx.x;
  int r = n0;
  while (r < nend) {
    int g = batch[r];
    int segend = gstart[g + 1]; if (segend > nend) segend = nend;
    float a0 = 0.f, a1 = 0.f, a2 = 0.f, a3 = 0.f;
    for (; r + 3 < segend; r += 4) {
      a0 += bf2f(h[(size_t)r * 128 + tid]);
      a1 += bf2f(h[(size_t)(r + 1) * 128 + tid]);
      a2 += bf2f(h[(size_t)(r + 2) * 128 + tid]);
      a3 += bf2f(h[(size_t)(r + 3) * 128 + tid]);
    }
    for (; r < segend; ++r) a0 += bf2f(h[(size_t)r * 128 + tid]);
    atomicAdd(&reprs[g * 128 + tid], (a0 + a1) + (a2 + a3));
  }
}

// ---------------- head MLP + log_softmax -------------------------------------
__global__ __launch_bounds__(128) void head_kernel(const float* __restrict__ reprs,
                                                   const float* __restrict__ pw1,
                                                   const float* __restrict__ pb1,
                                                   const float* __restrict__ pw2,
                                                   const float* __restrict__ pb2,
                                                   float* __restrict__ out) {
  __shared__ float r[128], t1[128], z[NCLS];
  int g = blockIdx.x, tid = threadIdx.x;
  r[tid] = reprs[g * 128 + tid];
  __syncthreads();
  float acc = pb1[tid];
  for (int k = 0; k < 128; ++k) acc = fmaf(r[k], pw1[k * 128 + tid], acc);
  t1[tid] = fmaxf(acc, 0.f);
  __syncthreads();
  if (tid < NCLS) {
    float zz = pb2[tid];
    for (int k = 0; k < 128; ++k) zz = fmaf(t1[k], pw2[k * NCLS + tid], zz);
    z[tid] = zz;
  }
  __syncthreads();
  if (tid == 0) {
    float mx = -1e30f;
    for (int c = 0; c < NCLS; ++c) mx = fmaxf(mx, z[c]);
    float s = 0.f;
    for (int c = 0; c < NCLS; ++c) s += expf(z[c] - mx);
    float ls = logf(s) + mx;
    for (int c = 0; c < NCLS; ++c) out[g * NCLS + c] = z[c] - ls;
  }
}

extern "C" void kernel_launch(void* const* d_in, const int* in_sizes, int n_in,
                              void* d_out, int out_size, void* d_ws, size_t ws_size,
                              hipStream_t stream) {
  const float* x     = (const float*)d_in[0];
  const int*   eidx  = (const int*)d_in[1];
  const int*   batch = (const int*)d_in[2];
  const float* pre_w = (const float*)d_in[3];
  const float* pre_b = (const float*)d_in[4];
  const float* w1    = (const float*)d_in[5];
  const float* asrc1 = (const float*)d_in[6];
  const float* adst1 = (const float*)d_in[7];
  const float* b1    = (const float*)d_in[8];
  const float* w2    = (const float*)d_in[9];
  const float* asrc2 = (const float*)d_in[10];
  const float* adst2 = (const float*)d_in[11];
  const float* b2    = (const float*)d_in[12];
  const float* pw1   = (const float*)d_in[13];
  const float* pb1   = (const float*)d_in[14];
  const float* pw2   = (const float*)d_in[15];
  const float* pb2   = (const float*)d_in[16];
  float* out = (float*)d_out;

  const int* esrc = eidx;
  const int* edst = eidx + NEDGES;

  char* wsp = (char*)d_ws;
  size_t off = 0;
  auto alloc = [&](size_t bytes) -> void* {
    void* p = wsp + off;
    off += (bytes + 255) & ~(size_t)255;
    return p;
  };
  unsigned short* hb  = (unsigned short*)alloc((size_t)NNODES * 128 * 2);
  unsigned short* hwb = (unsigned short*)alloc((size_t)NNODES * 64 * 2);   // fp8 pairs
  float* a_s         = (float*)alloc((size_t)NNODES * 2 * 4);
  float* a_d         = (float*)alloc((size_t)NNODES * 2 * 4);
  float* reprs       = (float*)alloc((size_t)NGRAPH * 128 * 4);
  int* gstart        = (int*)alloc((NGRAPH + 1) * 4);
  int* row_ptr       = (int*)alloc(((size_t)NNODES + 1) * 4);
  int* colv          = (int*)alloc((size_t)NEDGES * 4);
  unsigned short* wt_pre = (unsigned short*)alloc((size_t)128 * FIN * 2);
  unsigned short* wt1    = (unsigned short*)alloc((size_t)128 * HDIM * 2);
  unsigned short* wt2    = (unsigned short*)alloc((size_t)128 * HDIM * 2);
  int* blockHist     = (int*)alloc((size_t)EBLK * NBUCK * 4);
  int* blockBaseCol  = (int*)alloc((size_t)NBUCK * EBLK * 4);
  int* bucket_total  = (int*)alloc(NBUCK * 4);
  int* bucket_ptr    = (int*)alloc((NBUCK + 1) * 4);
  unsigned* stagingG = (unsigned*)alloc((size_t)NEDGES * 4);

  int wb = NNODES / 4;             // wave-per-node kernels: 256 thr = 4 waves
  int sb = (NNODES + SEG_CHUNK - 1) / SEG_CHUNK;
  int gb = (NNODES + 63) / 64;     // 1563 GEMM blocks (64-row tiles)

  // one-shot weight conversion (bf16, transposed)
  convert_transpose<<<(FIN * 128 + 255) / 256, 256, 0, stream>>>(pre_w, wt_pre, FIN);
  convert_transpose<<<(HDIM * 128 + 255) / 256, 256, 0, stream>>>(w1, wt1, HDIM);
  convert_transpose<<<(HDIM * 128 + 255) / 256, 256, 0, stream>>>(w2, wt2, HDIM);

  // graph boundaries + zeroed pooling accumulator
  hipMemsetAsync(reprs, 0, (size_t)NGRAPH * 128 * 4, stream);
  find_starts<<<1, 256, 0, stream>>>(batch, gstart);

  // bucketed CSR build (packed 4B staging; fused deg-scan + scatter)
  bin_count<<<EBLK, 256, 0, stream>>>(edst, blockHist);
  colscan<<<NBUCK, 512, 0, stream>>>(blockHist, blockBaseCol, bucket_total);
  bscan<<<1, 128, 0, stream>>>(bucket_total, bucket_ptr);
  bin_place<<<EBLK, 512, 0, stream>>>(esrc, edst, blockBaseCol, bucket_ptr, stagingG);
  bucket_csr_fused<<<NBUCK, 1024, 0, stream>>>(stagingG, bucket_ptr, row_ptr, colv);

  // pre layer: h0 = relu(x @ pre_w + pre_b)  (bf16 h)
  gemm_mfma<<<gb, 256, 0, stream>>>(x, 0, wt_pre, pre_b, hb, nullptr,
                                    nullptr, nullptr, nullptr, nullptr, NNODES, FIN, 1);
  seg_sum_fast<<<sb, 128, 0, stream>>>(hb, batch, gstart, reprs);

  // GAT layer 1 (bf16 A; alpha fused into GEMM epilogue; fp8 value payload)
  gemm_mfma<<<gb, 256, 0, stream>>>(hb, 1, wt1, nullptr, nullptr, hwb,
                                    asrc1, adst1, a_s, a_d, NNODES, HDIM, 0);
  aggregate<<<wb, 256, 0, stream>>>(hwb, a_s, a_d, row_ptr, colv, b1, hb);
  seg_sum_fast<<<sb, 128, 0, stream>>>(hb, batch, gstart, reprs);

  // GAT layer 2
  gemm_mfma<<<gb, 256, 0, stream>>>(hb, 1, wt2, nullptr, nullptr, hwb,
                                    asrc2, adst2, a_s, a_d, NNODES, HDIM, 0);
  aggregate<<<wb, 256, 0, stream>>>(hwb, a_s, a_d, row_ptr, colv, b2, hb);
  seg_sum_fast<<<sb, 128, 0, stream>>>(hb, batch, gstart, reprs);

  // head
  head_kernel<<<NGRAPH, 128, 0, stream>>>(reprs, pw1, pb1, pw2, pb2, out);
}